// Round 2
// baseline (2038.356 us; speedup 1.0000x reference)
//
#include <hip/hip_runtime.h>
#include <hip/hip_bf16.h>
#include <math.h>

#define DIM 128
#define NATOMS 16384
#define NWORDS 16384
#define CAP 128          // padded-CSR max neighbors per row (mean 32.8, sigma 5.7 -> safe)
#define KW 11

__device__ __forceinline__ float bfu2f(unsigned short u) {
    unsigned int x = ((unsigned int)u) << 16;
    return __uint_as_float(x);
}

// ---------- zero a small accumulator region (256 floats) ----------
__global__ void k_zero256(float* __restrict__ p) {
    p[threadIdx.x] = 0.f;
}

// ---------- W[n][k] -> Wt[k][n], 128x128 ----------
__global__ void k_transpose128(const float* __restrict__ W, float* __restrict__ Wt) {
    int idx = blockIdx.x * 256 + threadIdx.x;   // 16384 total
    int n = idx >> 7, k = idx & 127;
    Wt[k * DIM + n] = W[n * DIM + k];
}

// ---------- out[i][:] = table[ids[i]][:] ----------
__global__ void k_gather(const int* __restrict__ ids, const float* __restrict__ table,
                         float* __restrict__ out) {
    int idx = blockIdx.x * 256 + threadIdx.x;   // nrows*128
    int i = idx >> 7, d = idx & 127;
    out[idx] = table[(size_t)ids[i] * DIM + d];
}

// ---------- dense f32 adjacency -> padded CSR (read 1.07GB exactly once) ----------
__global__ void k_csr(const float* __restrict__ adj, unsigned short* __restrict__ cols,
                      int* __restrict__ rowcnt) {
    __shared__ int cnt;
    int row = blockIdx.x;
    if (threadIdx.x == 0) cnt = 0;
    __syncthreads();
    const float4* rp = (const float4*)(adj + (size_t)row * NATOMS);
    unsigned short* rc = cols + (size_t)row * CAP;
    #pragma unroll
    for (int it = 0; it < NATOMS / 4 / 256; ++it) {     // 16 iters
        int vi = it * 256 + threadIdx.x;
        float4 v = rp[vi];
        int j0 = vi * 4;
        if (v.x != 0.f) { int p = atomicAdd(&cnt, 1); if (p < CAP) rc[p] = (unsigned short)(j0); }
        if (v.y != 0.f) { int p = atomicAdd(&cnt, 1); if (p < CAP) rc[p] = (unsigned short)(j0 + 1); }
        if (v.z != 0.f) { int p = atomicAdd(&cnt, 1); if (p < CAP) rc[p] = (unsigned short)(j0 + 2); }
        if (v.w != 0.f) { int p = atomicAdd(&cnt, 1); if (p < CAP) rc[p] = (unsigned short)(j0 + 3); }
    }
    __syncthreads();
    if (threadIdx.x == 0) rowcnt[row] = min(cnt, CAP);
}

// ---------- out_bf16[i][n] = relu(bias[n] + sum_k A[i][k]*Wt[k][n]); 8 rows/block ----------
__global__ void k_gemm_relu(const float* __restrict__ A, const float* __restrict__ Wt,
                            const float* __restrict__ bias, __hip_bfloat16* __restrict__ out) {
    __shared__ float a_s[8][DIM];
    int row0 = blockIdx.x * 8;
    int t = threadIdx.x;
    #pragma unroll
    for (int p = 0; p < 4; ++p) {
        int e = p * 256 + t;
        a_s[e >> 7][e & 127] = A[(size_t)(row0 + (e >> 7)) * DIM + (e & 127)];
    }
    __syncthreads();
    int n = t & 127;
    int rh = (t >> 7) * 4;            // 0 or 4
    float acc0 = 0.f, acc1 = 0.f, acc2 = 0.f, acc3 = 0.f;
    #pragma unroll 4
    for (int k = 0; k < DIM; ++k) {
        float w = Wt[k * DIM + n];    // coalesced; a_s reads are wave-broadcast
        acc0 += a_s[rh + 0][k] * w;
        acc1 += a_s[rh + 1][k] * w;
        acc2 += a_s[rh + 2][k] * w;
        acc3 += a_s[rh + 3][k] * w;
    }
    float b = bias[n];
    out[(size_t)(row0 + rh + 0) * DIM + n] = __float2bfloat16(fmaxf(acc0 + b, 0.f));
    out[(size_t)(row0 + rh + 1) * DIM + n] = __float2bfloat16(fmaxf(acc1 + b, 0.f));
    out[(size_t)(row0 + rh + 2) * DIM + n] = __float2bfloat16(fmaxf(acc2 + b, 0.f));
    out[(size_t)(row0 + rh + 3) * DIM + n] = __float2bfloat16(fmaxf(acc3 + b, 0.f));
}

// ---------- xs[row][:] += sum_{j in neigh(row)} hs[j][:] ----------
__global__ void k_spmm(float* __restrict__ xs, const unsigned short* __restrict__ cols,
                       const int* __restrict__ rowcnt, const __hip_bfloat16* __restrict__ hs) {
    int row = blockIdx.x;
    int d = threadIdx.x;              // 128 threads
    int cnt = rowcnt[row];
    const unsigned short* rc = cols + (size_t)row * CAP;
    const unsigned short* hu = (const unsigned short*)hs;
    float acc = 0.f;
    int e = 0;
    for (; e + 4 <= cnt; e += 4) {
        int j0 = rc[e], j1 = rc[e + 1], j2 = rc[e + 2], j3 = rc[e + 3];
        acc += bfu2f(hu[(size_t)j0 * DIM + d]);
        acc += bfu2f(hu[(size_t)j1 * DIM + d]);
        acc += bfu2f(hu[(size_t)j2 * DIM + d]);
        acc += bfu2f(hu[(size_t)j3 * DIM + d]);
    }
    for (; e < cnt; ++e) acc += bfu2f(hu[(size_t)rc[e] * DIM + d]);
    xs[(size_t)row * DIM + d] += acc;
}

// ---------- column sum of xs into csum[128] (mean later) ----------
__global__ void k_colsum(const float* __restrict__ xs, float* __restrict__ sum) {
    int d = threadIdx.x;              // 128
    int r0 = blockIdx.x * 128;        // grid 128
    float acc = 0.f;
    for (int r = 0; r < 128; ++r) acc += xs[(size_t)(r0 + r) * DIM + d];
    atomicAdd(&sum[d], acc);
}

// ---------- 11x11 conv (cross-correlation), zero pad 5 both dims, +bias, relu ----------
#define TY 16
__global__ void k_conv(const float* __restrict__ in, const float* __restrict__ kw,
                       const float* __restrict__ kb, float* __restrict__ out) {
    __shared__ float buf[TY + 10][144];
    __shared__ float kk[121];
    int t = threadIdx.x;              // 128 threads (one per output column)
    if (t < 121) kk[t] = kw[t];
    int y0 = blockIdx.x * TY;
    for (int rr = 0; rr < TY + 10; ++rr) {
        int r = y0 - 5 + rr;
        bool rok = (r >= 0 && r < NWORDS);
        {
            int xi = t - 5;
            buf[rr][t] = (rok && xi >= 0) ? in[(size_t)r * DIM + xi] : 0.f;
        }
        if (t < 10) {
            int xi = t + 123;
            buf[rr][t + 128] = (rok && xi < DIM) ? in[(size_t)r * DIM + xi] : 0.f;
        }
    }
    __syncthreads();
    float acc[TY];
    #pragma unroll
    for (int o = 0; o < TY; ++o) acc[o] = 0.f;
    float bias = kb[0];
    #pragma unroll
    for (int rr = 0; rr < TY + 10; ++rr) {
        float v[KW];
        #pragma unroll
        for (int dx = 0; dx < KW; ++dx) v[dx] = buf[rr][t + dx];
        #pragma unroll
        for (int dy = 0; dy < KW; ++dy) {
            int o = rr - dy;          // compile-time after unroll
            if (o >= 0 && o < TY) {
                float s = 0.f;
                #pragma unroll
                for (int dx = 0; dx < KW; ++dx) s += v[dx] * kk[dy * KW + dx];
                acc[o] += s;
            }
        }
    }
    #pragma unroll
    for (int o = 0; o < TY; ++o)
        out[(size_t)(y0 + o) * DIM + t] = fmaxf(acc[o] + bias, 0.f);
}

// ---------- h[n] = relu(ba[n] + sum_k (csum[k]/N) * Wa[n][k]) ----------
__global__ void k_hvec(const float* __restrict__ csum, const float* __restrict__ Wa,
                       const float* __restrict__ ba, float* __restrict__ h) {
    __shared__ float c[DIM];
    int t = threadIdx.x;              // 128
    c[t] = csum[t] * (1.f / (float)NATOMS);
    __syncthreads();
    float acc = ba[t];
    for (int k = 0; k < DIM; ++k) acc += c[k] * Wa[t * DIM + k];
    h[t] = fmaxf(acc, 0.f);
}

// ---------- protein_sum[d] = sum_l tanh(h . hs[l]) * hs[l][d] ----------
__global__ void k_attnpool(const __hip_bfloat16* __restrict__ hs, const float* __restrict__ h,
                           float* __restrict__ psum) {
    __shared__ float ls[DIM];
    int t = threadIdx.x;              // 256
    if (t < DIM) ls[t] = 0.f;
    __syncthreads();
    int lane = t & 63;
    int wave = blockIdx.x * 4 + (t >> 6);   // grid 128 -> 512 waves
    int d0 = lane * 2;
    float h0 = h[d0], h1 = h[d0 + 1];
    const unsigned short* hu = (const unsigned short*)hs;
    float a0 = 0.f, a1 = 0.f;
    for (int r = wave; r < NWORDS; r += 512) {
        ushort2 uv = *(const ushort2*)(hu + (size_t)r * DIM + d0);
        float v0 = bfu2f(uv.x), v1 = bfu2f(uv.y);
        float p = h0 * v0 + h1 * v1;
        #pragma unroll
        for (int m = 32; m >= 1; m >>= 1) p += __shfl_xor(p, m, 64);
        float w = tanhf(p);
        a0 += w * v0;
        a1 += w * v1;
    }
    atomicAdd(&ls[d0], a0);
    atomicAdd(&ls[d0 + 1], a1);
    __syncthreads();
    if (t < DIM) atomicAdd(&psum[t], ls[t]);
}

// ---------- final MLP: cat=[csum/N, psum/N]; 2x relu(cat@Wo.T+bo); out=cat@Wi.T+bi ----------
__global__ void k_mlp(const float* __restrict__ csum, const float* __restrict__ psum,
                      const float* __restrict__ Wo, const float* __restrict__ bo,
                      const float* __restrict__ Wi, const float* __restrict__ bi,
                      float* __restrict__ out) {
    __shared__ float cat[256];
    __shared__ float nxt[256];
    int t = threadIdx.x;              // 256
    cat[t] = (t < DIM ? csum[t] : psum[t - DIM]) * (1.f / 16384.f);
    __syncthreads();
    for (int L = 0; L < 2; ++L) {
        float acc = bo[t];
        for (int k = 0; k < 256; ++k) acc += cat[k] * Wo[t * 256 + k];
        nxt[t] = fmaxf(acc, 0.f);
        __syncthreads();
        cat[t] = nxt[t];
        __syncthreads();
    }
    if (t < 2) {
        float acc = bi[t];
        for (int k = 0; k < 256; ++k) acc += cat[k] * Wi[t * 256 + k];
        out[t] = acc;
    }
}

extern "C" void kernel_launch(void* const* d_in, const int* in_sizes, int n_in,
                              void* d_out, int out_size, void* d_ws, size_t ws_size,
                              hipStream_t stream) {
    const int*   fingerprints = (const int*)  d_in[0];
    const float* adj          = (const float*)d_in[1];
    const int*   words        = (const int*)  d_in[2];
    const float* embed_fp     = (const float*)d_in[3];
    const float* embed_word   = (const float*)d_in[4];
    const float* Wg           = (const float*)d_in[5];
    const float* bg           = (const float*)d_in[6];
    const float* convk        = (const float*)d_in[7];
    const float* convb        = (const float*)d_in[8];
    const float* Wa           = (const float*)d_in[9];
    const float* ba           = (const float*)d_in[10];
    const float* Wo           = (const float*)d_in[11];
    const float* bo           = (const float*)d_in[12];
    const float* Wi           = (const float*)d_in[13];
    const float* bi           = (const float*)d_in[14];
    float* out = (float*)d_out;

    char* ws = (char*)d_ws;
    float*            xs     = (float*)           (ws + 0);          //  8 MB  [16384][128] f32
    __hip_bfloat16*   hsb    = (__hip_bfloat16*)  (ws + 8388608);    //  4 MB  [16384][128] bf16
    unsigned short*   cols   = (unsigned short*)  (ws + 12582912);   //  4 MB  [16384][CAP] u16
    int*              rowcnt = (int*)             (ws + 16777216);   // 64 KB
    float*            imgA   = (float*)           (ws + 16842752);   //  8 MB
    float*            imgB   = (float*)           (ws + 25231360);   //  8 MB
    __hip_bfloat16*   hsp    = (__hip_bfloat16*)  (ws + 33619968);   //  4 MB
    float*            Wtg    = (float*)           (ws + 37814272);   // 64 KB
    float*            Wta    = (float*)           (ws + 37879808);   // 64 KB
    float*            csum   = (float*)           (ws + 37945344);   // 512 B
    float*            psum   = (float*)           (ws + 37945856);   // 512 B
    float*            hvec   = (float*)           (ws + 37946368);   // 512 B
    // total ws usage ~38 MB

    k_zero256<<<1, 256, 0, stream>>>(csum);                      // zeros csum+psum (contiguous)
    k_transpose128<<<64, 256, 0, stream>>>(Wg, Wtg);
    k_transpose128<<<64, 256, 0, stream>>>(Wa, Wta);
    k_gather<<<8192, 256, 0, stream>>>(fingerprints, embed_fp, xs);
    k_csr<<<16384, 256, 0, stream>>>(adj, cols, rowcnt);

    for (int l = 0; l < 3; ++l) {
        k_gemm_relu<<<2048, 256, 0, stream>>>(xs, Wtg, bg, hsb);
        k_spmm<<<16384, 128, 0, stream>>>(xs, cols, rowcnt, hsb);
    }
    k_colsum<<<128, 128, 0, stream>>>(xs, csum);

    k_gather<<<8192, 256, 0, stream>>>(words, embed_word, imgA);
    k_conv<<<1024, 128, 0, stream>>>(imgA, convk, convb, imgB);
    k_conv<<<1024, 128, 0, stream>>>(imgB, convk, convb, imgA);
    k_conv<<<1024, 128, 0, stream>>>(imgA, convk, convb, imgB);

    k_gemm_relu<<<2048, 256, 0, stream>>>(imgB, Wta, ba, hsp);
    k_hvec<<<1, 128, 0, stream>>>(csum, Wa, ba, hvec);
    k_attnpool<<<128, 256, 0, stream>>>(hsp, hvec, psum);
    k_mlp<<<1, 256, 0, stream>>>(csum, psum, Wo, bo, Wi, bi, out);
}

// Round 3
// 1969.776 us; speedup vs baseline: 1.0348x; 1.0348x over previous
//
#include <hip/hip_runtime.h>
#include <hip/hip_bf16.h>
#include <math.h>

#define DIM 128
#define NATOMS 16384
#define NWORDS 16384
#define CAP 128          // padded-CSR max neighbors per row (mean 32.8, sigma 5.7 -> safe)
#define KW 11

typedef float f32x4 __attribute__((ext_vector_type(4)));
typedef __bf16 bf16x8 __attribute__((ext_vector_type(8)));
typedef unsigned short us8 __attribute__((ext_vector_type(8)));

__device__ __forceinline__ float bfu2f(unsigned short u) {
    unsigned int x = ((unsigned int)u) << 16;
    return __uint_as_float(x);
}
__device__ __forceinline__ unsigned short f2bf(float f) {   // RNE, finite inputs
    unsigned int x = __float_as_uint(f);
    unsigned int r = (x + 0x7fffu + ((x >> 16) & 1u)) >> 16;
    return (unsigned short)r;
}

// ---------- one-time prep: Wg,Wa -> bf16 copies; Wo -> WoT; zero csum/psum ----------
__global__ void k_prep(const float* __restrict__ Wg, const float* __restrict__ Wa,
                       const float* __restrict__ Wo,
                       unsigned short* __restrict__ Wgbf, unsigned short* __restrict__ Wabf,
                       float* __restrict__ WoT, float* __restrict__ zeros) {
    int idx = blockIdx.x * 256 + threadIdx.x;          // 385 blocks -> 98560
    if (idx < 16384) {
        Wgbf[idx] = f2bf(Wg[idx]);
    } else if (idx < 32768) {
        int e = idx - 16384;
        Wabf[e] = f2bf(Wa[e]);
    } else if (idx < 98304) {
        int e = idx - 32768;                           // Wo is [256][256]
        int r = e >> 8, c = e & 255;
        WoT[c * 256 + r] = Wo[e];
    } else if (idx < 98560) {
        zeros[idx - 98304] = 0.f;                      // csum[128] + psum[128]
    }
}

// ---------- out[i][:] = table[ids[i]][:] ----------
__global__ void k_gather(const int* __restrict__ ids, const float* __restrict__ table,
                         float* __restrict__ out) {
    int idx = blockIdx.x * 256 + threadIdx.x;   // nrows*128
    int i = idx >> 7, d = idx & 127;
    out[idx] = table[(size_t)ids[i] * DIM + d];
}

// ---------- dense f32 adjacency -> padded CSR (read 1.07GB exactly once) ----------
__global__ void k_csr(const float* __restrict__ adj, unsigned short* __restrict__ cols,
                      int* __restrict__ rowcnt) {
    __shared__ int cnt;
    int row = blockIdx.x;
    if (threadIdx.x == 0) cnt = 0;
    __syncthreads();
    const float4* rp = (const float4*)(adj + (size_t)row * NATOMS);
    unsigned short* rc = cols + (size_t)row * CAP;
    #pragma unroll
    for (int it = 0; it < NATOMS / 4 / 256; ++it) {     // 16 iters
        int vi = it * 256 + threadIdx.x;
        float4 v = rp[vi];
        int j0 = vi * 4;
        if (v.x != 0.f) { int p = atomicAdd(&cnt, 1); if (p < CAP) rc[p] = (unsigned short)(j0); }
        if (v.y != 0.f) { int p = atomicAdd(&cnt, 1); if (p < CAP) rc[p] = (unsigned short)(j0 + 1); }
        if (v.z != 0.f) { int p = atomicAdd(&cnt, 1); if (p < CAP) rc[p] = (unsigned short)(j0 + 2); }
        if (v.w != 0.f) { int p = atomicAdd(&cnt, 1); if (p < CAP) rc[p] = (unsigned short)(j0 + 3); }
    }
    __syncthreads();
    if (threadIdx.x == 0) rowcnt[row] = min(cnt, CAP);
}

// ---------- MFMA bf16: out_bf16[16384][128] = relu(A_f32 @ Wbf^T + bias) ----------
// W stored [n][k] row-major (original torch layout) in bf16; B-frag k-contiguous.
// 16x16x32 frags: A/B lane l -> elem (l&15, (l>>4)*8+j); C/D lane l reg q -> (row=(l>>4)*4+q, col=l&15)
__global__ __launch_bounds__(256) void k_gemm_mfma(const float* __restrict__ A,
                                                   const unsigned short* __restrict__ Wbf,
                                                   const float* __restrict__ bias,
                                                   __hip_bfloat16* __restrict__ out) {
    int t = threadIdx.x;
    int wave = t >> 6, lane = t & 63;
    int m16 = lane & 15, kgrp = lane >> 4;              // kgrp 0..3
    int r0 = blockIdx.x * 64 + wave * 16;               // 256 blocks
    const float* arow = A + (size_t)(r0 + m16) * DIM;

    bf16x8 afrag[4];
    #pragma unroll
    for (int kb = 0; kb < 4; ++kb) {
        const float4* p = (const float4*)(arow + kb * 32 + kgrp * 8);
        float4 lo = p[0], hi = p[1];
        us8 u;
        u[0] = f2bf(lo.x); u[1] = f2bf(lo.y); u[2] = f2bf(lo.z); u[3] = f2bf(lo.w);
        u[4] = f2bf(hi.x); u[5] = f2bf(hi.y); u[6] = f2bf(hi.z); u[7] = f2bf(hi.w);
        union { us8 u; bf16x8 b; } cv; cv.u = u;
        afrag[kb] = cv.b;
    }

    unsigned short* outp = (unsigned short*)out;
    for (int nb = 0; nb < 8; ++nb) {
        int col = nb * 16 + m16;
        const unsigned short* brow = Wbf + (size_t)col * DIM;
        f32x4 acc = {0.f, 0.f, 0.f, 0.f};
        #pragma unroll
        for (int kb = 0; kb < 4; ++kb) {
            union { us8 u; bf16x8 b; } cv;
            cv.u = *(const us8*)(brow + kb * 32 + kgrp * 8);
            acc = __builtin_amdgcn_mfma_f32_16x16x32_bf16(afrag[kb], cv.b, acc, 0, 0, 0);
        }
        float b = bias[col];
        #pragma unroll
        for (int q = 0; q < 4; ++q) {
            int row = r0 + kgrp * 4 + q;
            outp[(size_t)row * DIM + col] = f2bf(fmaxf(acc[q] + b, 0.f));
        }
    }
}

// ---------- xs[row][:] += sum_{j in neigh(row)} hs[j][:] ----------
__global__ void k_spmm(float* __restrict__ xs, const unsigned short* __restrict__ cols,
                       const int* __restrict__ rowcnt, const __hip_bfloat16* __restrict__ hs) {
    int row = blockIdx.x;
    int d = threadIdx.x;              // 128 threads
    int cnt = rowcnt[row];
    const unsigned short* rc = cols + (size_t)row * CAP;
    const unsigned short* hu = (const unsigned short*)hs;
    float acc = 0.f;
    int e = 0;
    for (; e + 4 <= cnt; e += 4) {
        int j0 = rc[e], j1 = rc[e + 1], j2 = rc[e + 2], j3 = rc[e + 3];
        acc += bfu2f(hu[(size_t)j0 * DIM + d]);
        acc += bfu2f(hu[(size_t)j1 * DIM + d]);
        acc += bfu2f(hu[(size_t)j2 * DIM + d]);
        acc += bfu2f(hu[(size_t)j3 * DIM + d]);
    }
    for (; e < cnt; ++e) acc += bfu2f(hu[(size_t)rc[e] * DIM + d]);
    xs[(size_t)row * DIM + d] += acc;
}

// ---------- column sum of xs into csum[128] ----------
__global__ void k_colsum(const float* __restrict__ xs, float* __restrict__ sum) {
    int d = threadIdx.x;              // 128
    int r0 = blockIdx.x * 128;        // grid 128
    float acc = 0.f;
    for (int r = 0; r < 128; ++r) acc += xs[(size_t)(r0 + r) * DIM + d];
    atomicAdd(&sum[d], acc);
}

// ---------- 11x11 conv (cross-correlation), zero pad 5 both dims, +bias, relu ----------
#define TY 16
__global__ void k_conv(const float* __restrict__ in, const float* __restrict__ kw,
                       const float* __restrict__ kb, float* __restrict__ out) {
    __shared__ float buf[TY + 10][144];
    __shared__ float kk[121];
    int t = threadIdx.x;              // 128 threads (one per output column)
    if (t < 121) kk[t] = kw[t];
    int y0 = blockIdx.x * TY;
    for (int rr = 0; rr < TY + 10; ++rr) {
        int r = y0 - 5 + rr;
        bool rok = (r >= 0 && r < NWORDS);
        {
            int xi = t - 5;
            buf[rr][t] = (rok && xi >= 0) ? in[(size_t)r * DIM + xi] : 0.f;
        }
        if (t < 10) {
            int xi = t + 123;
            buf[rr][t + 128] = (rok && xi < DIM) ? in[(size_t)r * DIM + xi] : 0.f;
        }
    }
    __syncthreads();
    float acc[TY];
    #pragma unroll
    for (int o = 0; o < TY; ++o) acc[o] = 0.f;
    float bias = kb[0];
    #pragma unroll
    for (int rr = 0; rr < TY + 10; ++rr) {
        float v[KW];
        #pragma unroll
        for (int dx = 0; dx < KW; ++dx) v[dx] = buf[rr][t + dx];
        #pragma unroll
        for (int dy = 0; dy < KW; ++dy) {
            int o = rr - dy;          // compile-time after unroll
            if (o >= 0 && o < TY) {
                float s = 0.f;
                #pragma unroll
                for (int dx = 0; dx < KW; ++dx) s += v[dx] * kk[dy * KW + dx];
                acc[o] += s;
            }
        }
    }
    #pragma unroll
    for (int o = 0; o < TY; ++o)
        out[(size_t)(y0 + o) * DIM + t] = fmaxf(acc[o] + bias, 0.f);
}

// ---------- h[n] = relu(ba[n] + sum_k (csum[k]/N) * Wa[n][k]) ----------
__global__ void k_hvec(const float* __restrict__ csum, const float* __restrict__ Wa,
                       const float* __restrict__ ba, float* __restrict__ h) {
    __shared__ float c[DIM];
    int t = threadIdx.x;              // 128
    c[t] = csum[t] * (1.f / (float)NATOMS);
    __syncthreads();
    float acc = ba[t];
    for (int k = 0; k < DIM; ++k) acc += c[k] * Wa[t * DIM + k];
    h[t] = fmaxf(acc, 0.f);
}

// ---------- protein_sum[d] = sum_l tanh(h . hs[l]) * hs[l][d] ----------
__global__ void k_attnpool(const __hip_bfloat16* __restrict__ hs, const float* __restrict__ h,
                           float* __restrict__ psum) {
    __shared__ float ls[DIM];
    int t = threadIdx.x;              // 256
    if (t < DIM) ls[t] = 0.f;
    __syncthreads();
    int lane = t & 63;
    int wave = blockIdx.x * 4 + (t >> 6);   // grid 128 -> 512 waves
    int d0 = lane * 2;
    float h0 = h[d0], h1 = h[d0 + 1];
    const unsigned short* hu = (const unsigned short*)hs;
    float a0 = 0.f, a1 = 0.f;
    for (int r = wave; r < NWORDS; r += 512) {
        ushort2 uv = *(const ushort2*)(hu + (size_t)r * DIM + d0);
        float v0 = bfu2f(uv.x), v1 = bfu2f(uv.y);
        float p = h0 * v0 + h1 * v1;
        #pragma unroll
        for (int m = 32; m >= 1; m >>= 1) p += __shfl_xor(p, m, 64);
        float w = tanhf(p);
        a0 += w * v0;
        a1 += w * v1;
    }
    atomicAdd(&ls[d0], a0);
    atomicAdd(&ls[d0 + 1], a1);
    __syncthreads();
    if (t < DIM) atomicAdd(&psum[t], ls[t]);
}

// ---------- final MLP: cat=[csum/N, psum/N]; 2x relu(cat@Wo.T+bo); out=cat@Wi.T+bi ----------
__global__ void k_mlp(const float* __restrict__ csum, const float* __restrict__ psum,
                      const float* __restrict__ WoT, const float* __restrict__ bo,
                      const float* __restrict__ Wi, const float* __restrict__ bi,
                      float* __restrict__ out) {
    __shared__ float cat[256];
    __shared__ float nxt[256];
    int t = threadIdx.x;              // 256
    cat[t] = (t < DIM ? csum[t] : psum[t - DIM]) * (1.f / 16384.f);
    __syncthreads();
    for (int L = 0; L < 2; ++L) {
        float acc = bo[t];
        for (int k = 0; k < 256; ++k) acc += cat[k] * WoT[k * 256 + t];   // coalesced
        nxt[t] = fmaxf(acc, 0.f);
        __syncthreads();
        cat[t] = nxt[t];
        __syncthreads();
    }
    if (t < 2) {
        float acc = bi[t];
        for (int k = 0; k < 256; ++k) acc += cat[k] * Wi[t * 256 + k];
        out[t] = acc;
    }
}

extern "C" void kernel_launch(void* const* d_in, const int* in_sizes, int n_in,
                              void* d_out, int out_size, void* d_ws, size_t ws_size,
                              hipStream_t stream) {
    const int*   fingerprints = (const int*)  d_in[0];
    const float* adj          = (const float*)d_in[1];
    const int*   words        = (const int*)  d_in[2];
    const float* embed_fp     = (const float*)d_in[3];
    const float* embed_word   = (const float*)d_in[4];
    const float* Wg           = (const float*)d_in[5];
    const float* bg           = (const float*)d_in[6];
    const float* convk        = (const float*)d_in[7];
    const float* convb        = (const float*)d_in[8];
    const float* Wa           = (const float*)d_in[9];
    const float* ba           = (const float*)d_in[10];
    const float* Wo           = (const float*)d_in[11];
    const float* bo           = (const float*)d_in[12];
    const float* Wi           = (const float*)d_in[13];
    const float* bi           = (const float*)d_in[14];
    float* out = (float*)d_out;

    char* ws = (char*)d_ws;
    float*            xs     = (float*)           (ws + 0);          //  8 MB
    __hip_bfloat16*   hsb    = (__hip_bfloat16*)  (ws + 8388608);    //  4 MB
    unsigned short*   cols   = (unsigned short*)  (ws + 12582912);   //  4 MB
    int*              rowcnt = (int*)             (ws + 16777216);   // 64 KB
    float*            imgA   = (float*)           (ws + 16842752);   //  8 MB
    float*            imgB   = (float*)           (ws + 25231360);   //  8 MB
    __hip_bfloat16*   hsp    = (__hip_bfloat16*)  (ws + 33619968);   //  4 MB
    unsigned short*   Wgbf   = (unsigned short*)  (ws + 37814272);   // 32 KB
    unsigned short*   Wabf   = (unsigned short*)  (ws + 37847040);   // 32 KB
    float*            WoT    = (float*)           (ws + 37879808);   // 256 KB
    float*            csum   = (float*)           (ws + 38141952);   // 512 B
    float*            psum   = (float*)           (ws + 38142464);   // 512 B
    float*            hvec   = (float*)           (ws + 38142976);   // 512 B

    k_prep<<<385, 256, 0, stream>>>(Wg, Wa, Wo, Wgbf, Wabf, WoT, csum);
    k_gather<<<8192, 256, 0, stream>>>(fingerprints, embed_fp, xs);
    k_csr<<<16384, 256, 0, stream>>>(adj, cols, rowcnt);

    for (int l = 0; l < 3; ++l) {
        k_gemm_mfma<<<256, 256, 0, stream>>>(xs, Wgbf, bg, hsb);
        k_spmm<<<16384, 128, 0, stream>>>(xs, cols, rowcnt, hsb);
    }
    k_colsum<<<128, 128, 0, stream>>>(xs, csum);

    k_gather<<<8192, 256, 0, stream>>>(words, embed_word, imgA);
    k_conv<<<1024, 128, 0, stream>>>(imgA, convk, convb, imgB);
    k_conv<<<1024, 128, 0, stream>>>(imgB, convk, convb, imgA);
    k_conv<<<1024, 128, 0, stream>>>(imgA, convk, convb, imgB);

    k_gemm_mfma<<<256, 256, 0, stream>>>(imgB, Wabf, ba, hsp);
    k_hvec<<<1, 128, 0, stream>>>(csum, Wa, ba, hvec);
    k_attnpool<<<128, 256, 0, stream>>>(hsp, hvec, psum);
    k_mlp<<<1, 256, 0, stream>>>(csum, psum, WoT, bo, Wi, bi, out);
}

// Round 4
// 1945.904 us; speedup vs baseline: 1.0475x; 1.0123x over previous
//
#include <hip/hip_runtime.h>
#include <hip/hip_bf16.h>
#include <math.h>

#define DIM 128
#define NATOMS 16384
#define NWORDS 16384
#define CAP 128          // padded-CSR max neighbors per row (mean 32.8, sigma 5.7 -> safe)
#define KW 11

typedef float f32x4 __attribute__((ext_vector_type(4)));
typedef __bf16 bf16x8 __attribute__((ext_vector_type(8)));
typedef unsigned short us8 __attribute__((ext_vector_type(8)));

__device__ __forceinline__ float bfu2f(unsigned short u) {
    unsigned int x = ((unsigned int)u) << 16;
    return __uint_as_float(x);
}
__device__ __forceinline__ unsigned short f2bf(float f) {   // RNE, finite inputs
    unsigned int x = __float_as_uint(f);
    unsigned int r = (x + 0x7fffu + ((x >> 16) & 1u)) >> 16;
    return (unsigned short)r;
}

// ---------- one-time prep: Wg,Wa -> bf16 copies; Wo -> WoT; zero csum/psum ----------
__global__ void k_prep(const float* __restrict__ Wg, const float* __restrict__ Wa,
                       const float* __restrict__ Wo,
                       unsigned short* __restrict__ Wgbf, unsigned short* __restrict__ Wabf,
                       float* __restrict__ WoT, float* __restrict__ zeros) {
    int idx = blockIdx.x * 256 + threadIdx.x;          // 385 blocks -> 98560
    if (idx < 16384) {
        Wgbf[idx] = f2bf(Wg[idx]);
    } else if (idx < 32768) {
        int e = idx - 16384;
        Wabf[e] = f2bf(Wa[e]);
    } else if (idx < 98304) {
        int e = idx - 32768;                           // Wo is [256][256]
        int r = e >> 8, c = e & 255;
        WoT[c * 256 + r] = Wo[e];
    } else if (idx < 98560) {
        zeros[idx - 98304] = 0.f;                      // csum[128] + psum[128]
    }
}

// ---------- both gathers in one launch: out[i][:] = table[ids[i]][:] ----------
__global__ void k_gather2(const int* __restrict__ ids1, const float* __restrict__ tab1,
                          float* __restrict__ out1,
                          const int* __restrict__ ids2, const float* __restrict__ tab2,
                          float* __restrict__ out2) {
    int b = blockIdx.x;
    const int* ids; const float* tab; float* out;
    if (b < 8192) { ids = ids1; tab = tab1; out = out1; }
    else          { b -= 8192; ids = ids2; tab = tab2; out = out2; }
    int idx = b * 256 + threadIdx.x;            // 16384*128 elems per half
    int i = idx >> 7, d = idx & 127;
    out[idx] = tab[(size_t)ids[i] * DIM + d];
}

// ---------- dense f32 adjacency -> padded CSR (read 1.07GB exactly once) ----------
__global__ void k_csr(const float* __restrict__ adj, unsigned short* __restrict__ cols,
                      int* __restrict__ rowcnt) {
    __shared__ int cnt;
    int row = blockIdx.x;
    if (threadIdx.x == 0) cnt = 0;
    __syncthreads();
    const float4* rp = (const float4*)(adj + (size_t)row * NATOMS);
    unsigned short* rc = cols + (size_t)row * CAP;
    #pragma unroll
    for (int it = 0; it < NATOMS / 4 / 256; ++it) {     // 16 iters
        int vi = it * 256 + threadIdx.x;
        float4 v = rp[vi];
        int j0 = vi * 4;
        if (v.x != 0.f) { int p = atomicAdd(&cnt, 1); if (p < CAP) rc[p] = (unsigned short)(j0); }
        if (v.y != 0.f) { int p = atomicAdd(&cnt, 1); if (p < CAP) rc[p] = (unsigned short)(j0 + 1); }
        if (v.z != 0.f) { int p = atomicAdd(&cnt, 1); if (p < CAP) rc[p] = (unsigned short)(j0 + 2); }
        if (v.w != 0.f) { int p = atomicAdd(&cnt, 1); if (p < CAP) rc[p] = (unsigned short)(j0 + 3); }
    }
    __syncthreads();
    if (threadIdx.x == 0) rowcnt[row] = min(cnt, CAP);
}

// ---------- MFMA bf16: out_bf16[16384][128] = relu(A_f32 @ Wbf^T + bias) ----------
// W stored [n][k] row-major (original torch layout) in bf16; B-frag k-contiguous.
// 16x16x32 frags: A/B lane l -> elem (l&15, (l>>4)*8+j); C/D lane l reg q -> (row=(l>>4)*4+q, col=l&15)
__global__ __launch_bounds__(256) void k_gemm_mfma(const float* __restrict__ A,
                                                   const unsigned short* __restrict__ Wbf,
                                                   const float* __restrict__ bias,
                                                   __hip_bfloat16* __restrict__ out) {
    int t = threadIdx.x;
    int wave = t >> 6, lane = t & 63;
    int m16 = lane & 15, kgrp = lane >> 4;              // kgrp 0..3
    int r0 = blockIdx.x * 64 + wave * 16;               // 256 blocks
    const float* arow = A + (size_t)(r0 + m16) * DIM;

    bf16x8 afrag[4];
    #pragma unroll
    for (int kb = 0; kb < 4; ++kb) {
        const float4* p = (const float4*)(arow + kb * 32 + kgrp * 8);
        float4 lo = p[0], hi = p[1];
        us8 u;
        u[0] = f2bf(lo.x); u[1] = f2bf(lo.y); u[2] = f2bf(lo.z); u[3] = f2bf(lo.w);
        u[4] = f2bf(hi.x); u[5] = f2bf(hi.y); u[6] = f2bf(hi.z); u[7] = f2bf(hi.w);
        union { us8 u; bf16x8 b; } cv; cv.u = u;
        afrag[kb] = cv.b;
    }

    unsigned short* outp = (unsigned short*)out;
    for (int nb = 0; nb < 8; ++nb) {
        int col = nb * 16 + m16;
        const unsigned short* brow = Wbf + (size_t)col * DIM;
        f32x4 acc = {0.f, 0.f, 0.f, 0.f};
        #pragma unroll
        for (int kb = 0; kb < 4; ++kb) {
            union { us8 u; bf16x8 b; } cv;
            cv.u = *(const us8*)(brow + kb * 32 + kgrp * 8);
            acc = __builtin_amdgcn_mfma_f32_16x16x32_bf16(afrag[kb], cv.b, acc, 0, 0, 0);
        }
        float b = bias[col];
        #pragma unroll
        for (int q = 0; q < 4; ++q) {
            int row = r0 + kgrp * 4 + q;
            outp[(size_t)row * DIM + col] = f2bf(fmaxf(acc[q] + b, 0.f));
        }
    }
}

// ---------- xs[row][:] += sum_{j in neigh(row)} hs[j][:]  (1 wave per row, 4 rows/block) ----------
__global__ __launch_bounds__(256) void k_spmm(float* __restrict__ xs,
                       const unsigned short* __restrict__ cols,
                       const int* __restrict__ rowcnt, const __hip_bfloat16* __restrict__ hs) {
    int t = threadIdx.x;
    int lane = t & 63;
    int row = blockIdx.x * 4 + (t >> 6);         // wave-uniform
    int cnt = rowcnt[row];
    const unsigned short* rc = cols + (size_t)row * CAP;
    const unsigned int* h32 = (const unsigned int*)hs;   // [NATOMS][64] packed bf16x2
    float a0 = 0.f, a1 = 0.f;
    int e = 0;
    for (; e + 4 <= cnt; e += 4) {
        int j0 = rc[e], j1 = rc[e + 1], j2 = rc[e + 2], j3 = rc[e + 3];
        unsigned int v0 = h32[(size_t)j0 * 64 + lane];
        unsigned int v1 = h32[(size_t)j1 * 64 + lane];
        unsigned int v2 = h32[(size_t)j2 * 64 + lane];
        unsigned int v3 = h32[(size_t)j3 * 64 + lane];
        a0 += bfu2f((unsigned short)v0); a1 += bfu2f((unsigned short)(v0 >> 16));
        a0 += bfu2f((unsigned short)v1); a1 += bfu2f((unsigned short)(v1 >> 16));
        a0 += bfu2f((unsigned short)v2); a1 += bfu2f((unsigned short)(v2 >> 16));
        a0 += bfu2f((unsigned short)v3); a1 += bfu2f((unsigned short)(v3 >> 16));
    }
    for (; e < cnt; ++e) {
        unsigned int v = h32[(size_t)rc[e] * 64 + lane];
        a0 += bfu2f((unsigned short)v); a1 += bfu2f((unsigned short)(v >> 16));
    }
    float2* xp = (float2*)(xs + (size_t)row * DIM);
    float2 o = xp[lane];
    o.x += a0; o.y += a1;
    xp[lane] = o;
}

// ---------- column sum of xs into csum[128] ----------
__global__ void k_colsum(const float* __restrict__ xs, float* __restrict__ sum) {
    int d = threadIdx.x;              // 128
    int r0 = blockIdx.x * 128;        // grid 128
    float acc = 0.f;
    for (int r = 0; r < 128; ++r) acc += xs[(size_t)(r0 + r) * DIM + d];
    atomicAdd(&sum[d], acc);
}

// ---------- 11x11 conv (cross-correlation), zero pad 5 both dims, +bias, relu ----------
#define TY 16
__global__ void k_conv(const float* __restrict__ in, const float* __restrict__ kw,
                       const float* __restrict__ kb, float* __restrict__ out) {
    __shared__ float buf[TY + 10][144];
    __shared__ float kk[121];
    int t = threadIdx.x;              // 128 threads (one per output column)
    if (t < 121) kk[t] = kw[t];
    int y0 = blockIdx.x * TY;
    for (int rr = 0; rr < TY + 10; ++rr) {
        int r = y0 - 5 + rr;
        bool rok = (r >= 0 && r < NWORDS);
        {
            int xi = t - 5;
            buf[rr][t] = (rok && xi >= 0) ? in[(size_t)r * DIM + xi] : 0.f;
        }
        if (t < 10) {
            int xi = t + 123;
            buf[rr][t + 128] = (rok && xi < DIM) ? in[(size_t)r * DIM + xi] : 0.f;
        }
    }
    __syncthreads();
    float acc[TY];
    #pragma unroll
    for (int o = 0; o < TY; ++o) acc[o] = 0.f;
    float bias = kb[0];
    #pragma unroll
    for (int rr = 0; rr < TY + 10; ++rr) {
        float v[KW];
        #pragma unroll
        for (int dx = 0; dx < KW; ++dx) v[dx] = buf[rr][t + dx];
        #pragma unroll
        for (int dy = 0; dy < KW; ++dy) {
            int o = rr - dy;          // compile-time after unroll
            if (o >= 0 && o < TY) {
                float s = 0.f;
                #pragma unroll
                for (int dx = 0; dx < KW; ++dx) s += v[dx] * kk[dy * KW + dx];
                acc[o] += s;
            }
        }
    }
    #pragma unroll
    for (int o = 0; o < TY; ++o)
        out[(size_t)(y0 + o) * DIM + t] = fmaxf(acc[o] + bias, 0.f);
}

// ---------- h[n] = relu(ba[n] + sum_k (csum[k]/N) * Wa[n][k]) ----------
__global__ void k_hvec(const float* __restrict__ csum, const float* __restrict__ Wa,
                       const float* __restrict__ ba, float* __restrict__ h) {
    __shared__ float c[DIM];
    int t = threadIdx.x;              // 128
    c[t] = csum[t] * (1.f / (float)NATOMS);
    __syncthreads();
    float acc = ba[t];
    for (int k = 0; k < DIM; ++k) acc += c[k] * Wa[t * DIM + k];
    h[t] = fmaxf(acc, 0.f);
}

// ---------- protein_sum[d] = sum_l tanh(h . hs[l]) * hs[l][d] ----------
__global__ void k_attnpool(const __hip_bfloat16* __restrict__ hs, const float* __restrict__ h,
                           float* __restrict__ psum) {
    __shared__ float ls[DIM];
    int t = threadIdx.x;              // 256
    if (t < DIM) ls[t] = 0.f;
    __syncthreads();
    int lane = t & 63;
    int wave = blockIdx.x * 4 + (t >> 6);   // grid 128 -> 512 waves
    int d0 = lane * 2;
    float h0 = h[d0], h1 = h[d0 + 1];
    const unsigned short* hu = (const unsigned short*)hs;
    float a0 = 0.f, a1 = 0.f;
    for (int r = wave; r < NWORDS; r += 512) {
        ushort2 uv = *(const ushort2*)(hu + (size_t)r * DIM + d0);
        float v0 = bfu2f(uv.x), v1 = bfu2f(uv.y);
        float p = h0 * v0 + h1 * v1;
        #pragma unroll
        for (int m = 32; m >= 1; m >>= 1) p += __shfl_xor(p, m, 64);
        float w = tanhf(p);
        a0 += w * v0;
        a1 += w * v1;
    }
    atomicAdd(&ls[d0], a0);
    atomicAdd(&ls[d0 + 1], a1);
    __syncthreads();
    if (t < DIM) atomicAdd(&psum[t], ls[t]);
}

// ---------- final MLP: cat=[csum/N, psum/N]; 2x relu(cat@Wo.T+bo); out=cat@Wi.T+bi ----------
__global__ void k_mlp(const float* __restrict__ csum, const float* __restrict__ psum,
                      const float* __restrict__ WoT, const float* __restrict__ bo,
                      const float* __restrict__ Wi, const float* __restrict__ bi,
                      float* __restrict__ out) {
    __shared__ float cat[256];
    __shared__ float nxt[256];
    int t = threadIdx.x;              // 256
    cat[t] = (t < DIM ? csum[t] : psum[t - DIM]) * (1.f / 16384.f);
    __syncthreads();
    for (int L = 0; L < 2; ++L) {
        float acc = bo[t];
        for (int k = 0; k < 256; ++k) acc += cat[k] * WoT[k * 256 + t];   // coalesced
        nxt[t] = fmaxf(acc, 0.f);
        __syncthreads();
        cat[t] = nxt[t];
        __syncthreads();
    }
    if (t < 2) {
        float acc = bi[t];
        for (int k = 0; k < 256; ++k) acc += cat[k] * Wi[t * 256 + k];
        out[t] = acc;
    }
}

extern "C" void kernel_launch(void* const* d_in, const int* in_sizes, int n_in,
                              void* d_out, int out_size, void* d_ws, size_t ws_size,
                              hipStream_t stream) {
    const int*   fingerprints = (const int*)  d_in[0];
    const float* adj          = (const float*)d_in[1];
    const int*   words        = (const int*)  d_in[2];
    const float* embed_fp     = (const float*)d_in[3];
    const float* embed_word   = (const float*)d_in[4];
    const float* Wg           = (const float*)d_in[5];
    const float* bg           = (const float*)d_in[6];
    const float* convk        = (const float*)d_in[7];
    const float* convb        = (const float*)d_in[8];
    const float* Wa           = (const float*)d_in[9];
    const float* ba           = (const float*)d_in[10];
    const float* Wo           = (const float*)d_in[11];
    const float* bo           = (const float*)d_in[12];
    const float* Wi           = (const float*)d_in[13];
    const float* bi           = (const float*)d_in[14];
    float* out = (float*)d_out;

    char* ws = (char*)d_ws;
    float*            xs     = (float*)           (ws + 0);          //  8 MB
    __hip_bfloat16*   hsb    = (__hip_bfloat16*)  (ws + 8388608);    //  4 MB
    unsigned short*   cols   = (unsigned short*)  (ws + 12582912);   //  4 MB
    int*              rowcnt = (int*)             (ws + 16777216);   // 64 KB
    float*            imgA   = (float*)           (ws + 16842752);   //  8 MB
    float*            imgB   = (float*)           (ws + 25231360);   //  8 MB
    __hip_bfloat16*   hsp    = (__hip_bfloat16*)  (ws + 33619968);   //  4 MB
    unsigned short*   Wgbf   = (unsigned short*)  (ws + 37814272);   // 32 KB
    unsigned short*   Wabf   = (unsigned short*)  (ws + 37847040);   // 32 KB
    float*            WoT    = (float*)           (ws + 37879808);   // 256 KB
    float*            csum   = (float*)           (ws + 38141952);   // 512 B
    float*            psum   = (float*)           (ws + 38142464);   // 512 B
    float*            hvec   = (float*)           (ws + 38142976);   // 512 B

    k_prep<<<385, 256, 0, stream>>>(Wg, Wa, Wo, Wgbf, Wabf, WoT, csum);
    k_gather2<<<16384, 256, 0, stream>>>(fingerprints, embed_fp, xs,
                                         words, embed_word, imgA);
    k_csr<<<16384, 256, 0, stream>>>(adj, cols, rowcnt);

    for (int l = 0; l < 3; ++l) {
        k_gemm_mfma<<<256, 256, 0, stream>>>(xs, Wgbf, bg, hsb);
        k_spmm<<<4096, 256, 0, stream>>>(xs, cols, rowcnt, hsb);
    }
    k_colsum<<<128, 128, 0, stream>>>(xs, csum);

    k_conv<<<1024, 128, 0, stream>>>(imgA, convk, convb, imgB);
    k_conv<<<1024, 128, 0, stream>>>(imgB, convk, convb, imgA);
    k_conv<<<1024, 128, 0, stream>>>(imgA, convk, convb, imgB);

    k_gemm_mfma<<<256, 256, 0, stream>>>(imgB, Wabf, ba, hsp);
    k_hvec<<<1, 128, 0, stream>>>(csum, Wa, ba, hvec);
    k_attnpool<<<128, 256, 0, stream>>>(hsp, hvec, psum);
    k_mlp<<<1, 256, 0, stream>>>(csum, psum, WoT, bo, Wi, bi, out);
}